// Round 3
// baseline (1082.917 us; speedup 1.0000x reference)
//
#include <hip/hip_runtime.h>
#include <stdint.h>

typedef __bf16 bf16x8 __attribute__((ext_vector_type(8)));
typedef float  f32x4  __attribute__((ext_vector_type(4)));

#define N_JOINT 21
#define TB 4
#define REAL_ROWS 84               // 21*4
#define RPAD 96                    // 6 MFMA M-tiles
#define BATCH 16384
#define TILES 8                    // tiles per block
#define NBLK (BATCH / (TB * TILES))   // 512 blocks
#define ZSTRIDE 129                // odd stride: bank = (r+c)%32, ~2-way

__device__ __forceinline__ uint32_t swz(uint32_t byteoff, uint32_t row) {
  return byteoff ^ ((row & 7u) << 4);
}
__device__ __forceinline__ uint16_t f2b(float v) {
  __bf16 b = (__bf16)v;
  return __builtin_bit_cast(uint16_t, b);
}

// (L z)[r][c], z in LDS row stride S floats. 21-joint hand tree.
// L[n][n]=1-1/deg, L[n][m]=-1/deg for nbrs; deg=#nbr+1.
__device__ __forceinline__ float lmix(const float* zbp, int S, int r, int c) {
  int e = r / 21;
  int n = r - e * 21;
  const float* rowb = zbp + e * 21 * S + c;
  float zv = rowb[n * S];
  float s = zv;
  float invd;
  if (n == 0) {
    s += rowb[1 * S] + rowb[5 * S] + rowb[9 * S] + rowb[13 * S] + rowb[17 * S];
    invd = 1.f / 6.f;
  } else {
    int p = (n - 1) & 3;
    if (p == 3) { s += rowb[(n - 1) * S]; invd = 0.5f; }
    else {
      int left = (p == 0) ? 0 : (n - 1);
      s += rowb[left * S] + rowb[(n + 1) * S];
      invd = 1.f / 3.f;
    }
  }
  return zv - invd * s;
}

// ---------------- prep: fp32 weights -> bf16 frag-layout in ws ----------------
// wf1[256][256] (n = concat(k0,k1) x Cout, k contiguous), wf2[256][128], wf3[16][128]
__global__ void prep_weights(const float* __restrict__ W1, const float* __restrict__ W2,
                             const float* __restrict__ W3, uint16_t* __restrict__ ws) {
  uint16_t* wf1 = ws;
  uint16_t* wf2 = ws + 65536;
  uint16_t* wf3 = ws + 65536 + 32768;
  for (int i = blockIdx.x * blockDim.x + threadIdx.x; i < 100352;
       i += gridDim.x * blockDim.x) {
    if (i < 65536) {
      int n = i >> 8, k = i & 255;
      float v = (n < 128) ? W1[k * 128 + n] : W1[32768 + k * 128 + (n - 128)];
      wf1[i] = f2b(v);
    } else if (i < 98304) {
      int j = i - 65536; int n = j >> 7, k = j & 127;
      float v = (n < 128) ? W2[k * 128 + n] : W2[16384 + k * 128 + (n - 128)];
      wf2[j] = f2b(v);
    } else {
      int j = i - 98304; int n = j >> 7, k = j & 127;
      float v = 0.f;
      if (n < 3)      v = W3[k * 3 + n];
      else if (n < 6) v = W3[384 + k * 3 + (n - 3)];
      wf3[j] = f2b(v);
    }
  }
}

// ---------------- fused main: weights in regs, persistent tiles ----------------
// NOTE: min-waves arg MUST be 1: (512,2) capped VGPRs at 128 and the 112-VGPR
// persistent weight set spilled (R2: WRITE_SIZE 583 MB, 2x slowdown).
__global__ __launch_bounds__(512, 1)
void cheb3_main(const float* __restrict__ xp,
                const uint16_t* __restrict__ wf1, const uint16_t* __restrict__ wf2,
                const uint16_t* __restrict__ wf3,
                const float* __restrict__ b1p, const float* __restrict__ b2p,
                const float* __restrict__ b3p, float* __restrict__ outp)
{
  __shared__ __align__(16) uint16_t sA[RPAD * 256];   // x bf16, swizzled (48 KB)
  __shared__ __align__(16) uint16_t sH[RPAD * 128];   // h bf16, swizzled (24 KB)
  __shared__ float zb[REAL_ROWS * ZSTRIDE];           // z fp32 (42.4 KB)

  const int tid  = threadIdx.x;
  const int wid  = tid >> 6;
  const int lane = tid & 63;
  const int l15  = lane & 15;
  const int lk   = lane >> 4;
  char* sAc = (char*)sA;
  char* sHc = (char*)sH;

  // persistent B-fragments (per-lane): wave owns u-col block [wid*16,+16) and
  // the matching z-col block (+128). 112 VGPRs.
  bf16x8 wB1[8][2], wB2[4][2], wB3[4];
  {
    const int nu = wid * 16 + l15;
    #pragma unroll
    for (int ch = 0; ch < 8; ++ch) {
      wB1[ch][0] = *(const bf16x8*)(wf1 + nu * 256 + ch * 32 + lk * 8);
      wB1[ch][1] = *(const bf16x8*)(wf1 + (nu + 128) * 256 + ch * 32 + lk * 8);
    }
    #pragma unroll
    for (int ch = 0; ch < 4; ++ch) {
      wB2[ch][0] = *(const bf16x8*)(wf2 + nu * 128 + ch * 32 + lk * 8);
      wB2[ch][1] = *(const bf16x8*)(wf2 + (nu + 128) * 128 + ch * 32 + lk * 8);
      wB3[ch]    = *(const bf16x8*)(wf3 + l15 * 128 + ch * 32 + lk * 8);
    }
  }
  const int   cu    = wid * 16 + l15;
  const float bias1 = b1p[cu];
  const float bias2 = b2p[cu];
  const float bias3 = (l15 < 3) ? b3p[l15] : 0.f;

  // zero pad rows 84..95 (written once, never touched again)
  {
    uint4 z16 = make_uint4(0, 0, 0, 0);
    for (int i = tid; i < (12 * 256) / 8; i += 512) {
      int f0 = i * 8, r = 84 + (f0 >> 8), c = f0 & 255;
      *(uint4*)(sAc + swz(r * 512 + c * 2, r)) = z16;
    }
    for (int i = tid; i < (12 * 128) / 8; i += 512) {
      int f0 = i * 8, r = 84 + (f0 >> 7), c = f0 & 127;
      *(uint4*)(sHc + swz(r * 256 + c * 2, r)) = z16;
    }
  }

  // stage tile 0 synchronously
  {
    const float* xg = xp + (size_t)(blockIdx.x * TILES) * (TB * N_JOINT * 256);
    #pragma unroll
    for (int j = 0; j < 6; ++j) {
      int i = tid + j * 512;
      if (i < 2688) {                       // 84 rows * 32 octs
        int r = i >> 5, c8 = (i & 31) * 8;
        float4 v0 = *(const float4*)(xg + r * 256 + c8);
        float4 v1 = *(const float4*)(xg + r * 256 + c8 + 4);
        bf16x8 o;
        o[0] = (__bf16)v0.x; o[1] = (__bf16)v0.y; o[2] = (__bf16)v0.z; o[3] = (__bf16)v0.w;
        o[4] = (__bf16)v1.x; o[5] = (__bf16)v1.y; o[6] = (__bf16)v1.z; o[7] = (__bf16)v1.w;
        *(bf16x8*)(sAc + swz(r * 512 + c8 * 2, r)) = o;
      }
    }
  }
  __syncthreads();

  const f32x4 zero4 = {0.f, 0.f, 0.f, 0.f};
  float4 pA[6], pB[6];                       // prefetch regs (octs 0..2 / 3..5)

  for (int t = 0; t < TILES; ++t) {
    const int gtile = blockIdx.x * TILES + t;
    const bool pf = (t + 1 < TILES);
    const float* xn = xp + (size_t)(gtile + 1) * (TB * N_JOINT * 256);

    // ---------------- LAYER 1: sA[96][256] @ wB1 ----------------
    f32x4 acc[6][2];
    #pragma unroll
    for (int mt = 0; mt < 6; ++mt) { acc[mt][0] = zero4; acc[mt][1] = zero4; }
    #pragma unroll
    for (int ch = 0; ch < 8; ++ch) {
      bf16x8 a[6];
      #pragma unroll
      for (int mt = 0; mt < 6; ++mt) {
        int r = mt * 16 + l15;
        a[mt] = *(const bf16x8*)(sAc + swz(r * 512 + ch * 64 + lk * 16, r));
      }
      #pragma unroll
      for (int nt = 0; nt < 2; ++nt)
        #pragma unroll
        for (int mt = 0; mt < 6; ++mt)
          acc[mt][nt] = __builtin_amdgcn_mfma_f32_16x16x32_bf16(a[mt], wB1[ch][nt], acc[mt][nt], 0, 0, 0);
    }

    // prefetch issue, group A (octs 0..2, always in range)
    if (pf) {
      #pragma unroll
      for (int j = 0; j < 3; ++j) {
        int i = tid + j * 512;
        int r = i >> 5, c8 = (i & 31) * 8;
        pA[2 * j]     = *(const float4*)(xn + r * 256 + c8);
        pA[2 * j + 1] = *(const float4*)(xn + r * 256 + c8 + 4);
      }
    }

    // mix1: z -> zb (all 8 waves)
    #pragma unroll
    for (int mt = 0; mt < 6; ++mt)
      #pragma unroll
      for (int rg = 0; rg < 4; ++rg) {
        int r = mt * 16 + lk * 4 + rg;
        if (r < REAL_ROWS) zb[r * ZSTRIDE + cu] = acc[mt][1][rg];
      }
    __syncthreads();                          // z visible; layer1 sA reads done

    if (pf) {                                 // write prefetched octs 0..2 (sA dead)
      #pragma unroll
      for (int j = 0; j < 3; ++j) {
        int i = tid + j * 512;
        int r = i >> 5, c8 = (i & 31) * 8;
        bf16x8 o;
        o[0] = (__bf16)pA[2*j].x; o[1] = (__bf16)pA[2*j].y; o[2] = (__bf16)pA[2*j].z; o[3] = (__bf16)pA[2*j].w;
        o[4] = (__bf16)pA[2*j+1].x; o[5] = (__bf16)pA[2*j+1].y; o[6] = (__bf16)pA[2*j+1].z; o[7] = (__bf16)pA[2*j+1].w;
        *(bf16x8*)(sAc + swz(r * 512 + c8 * 2, r)) = o;
      }
      #pragma unroll
      for (int j = 3; j < 6; ++j) {           // issue group B (octs 3..5)
        int i = tid + j * 512;
        if (i < 2688) {
          int r = i >> 5, c8 = (i & 31) * 8;
          pB[2 * (j-3)]     = *(const float4*)(xn + r * 256 + c8);
          pB[2 * (j-3) + 1] = *(const float4*)(xn + r * 256 + c8 + 4);
        }
      }
    }

    // mix1 compute: h1 = u + L z + b1, leaky -> sH
    #pragma unroll
    for (int mt = 0; mt < 6; ++mt)
      #pragma unroll
      for (int rg = 0; rg < 4; ++rg) {
        int r = mt * 16 + lk * 4 + rg;
        if (r < REAL_ROWS) {
          float h = acc[mt][0][rg] + lmix(zb, ZSTRIDE, r, cu) + bias1;
          h = (h > 0.f) ? h : 0.01f * h;
          *(uint16_t*)(sHc + swz(r * 256 + cu * 2, r)) = f2b(h);
        }
      }
    __syncthreads();                          // sH ready

    // ---------------- LAYER 2: sH[96][128] @ wB2 ----------------
    #pragma unroll
    for (int mt = 0; mt < 6; ++mt) { acc[mt][0] = zero4; acc[mt][1] = zero4; }
    #pragma unroll
    for (int ch = 0; ch < 4; ++ch) {
      bf16x8 a[6];
      #pragma unroll
      for (int mt = 0; mt < 6; ++mt) {
        int r = mt * 16 + l15;
        a[mt] = *(const bf16x8*)(sHc + swz(r * 256 + ch * 64 + lk * 16, r));
      }
      #pragma unroll
      for (int nt = 0; nt < 2; ++nt)
        #pragma unroll
        for (int mt = 0; mt < 6; ++mt)
          acc[mt][nt] = __builtin_amdgcn_mfma_f32_16x16x32_bf16(a[mt], wB2[ch][nt], acc[mt][nt], 0, 0, 0);
    }

    // mix2: z -> zb (WAR vs mix1 lmix reads: covered by pre-layer2 barrier)
    #pragma unroll
    for (int mt = 0; mt < 6; ++mt)
      #pragma unroll
      for (int rg = 0; rg < 4; ++rg) {
        int r = mt * 16 + lk * 4 + rg;
        if (r < REAL_ROWS) zb[r * ZSTRIDE + cu] = acc[mt][1][rg];
      }
    if (pf) {                                 // write prefetched octs 3..5
      #pragma unroll
      for (int j = 3; j < 6; ++j) {
        int i = tid + j * 512;
        if (i < 2688) {
          int r = i >> 5, c8 = (i & 31) * 8;
          bf16x8 o;
          o[0] = (__bf16)pB[2*(j-3)].x; o[1] = (__bf16)pB[2*(j-3)].y;
          o[2] = (__bf16)pB[2*(j-3)].z; o[3] = (__bf16)pB[2*(j-3)].w;
          o[4] = (__bf16)pB[2*(j-3)+1].x; o[5] = (__bf16)pB[2*(j-3)+1].y;
          o[6] = (__bf16)pB[2*(j-3)+1].z; o[7] = (__bf16)pB[2*(j-3)+1].w;
          *(bf16x8*)(sAc + swz(r * 512 + c8 * 2, r)) = o;
        }
      }
    }
    __syncthreads();                          // z2 visible; layer2 sH reads done

    // mix2 compute: h2 -> sH
    #pragma unroll
    for (int mt = 0; mt < 6; ++mt)
      #pragma unroll
      for (int rg = 0; rg < 4; ++rg) {
        int r = mt * 16 + lk * 4 + rg;
        if (r < REAL_ROWS) {
          float h = acc[mt][0][rg] + lmix(zb, ZSTRIDE, r, cu) + bias2;
          h = (h > 0.f) ? h : 0.01f * h;
          *(uint16_t*)(sHc + swz(r * 256 + cu * 2, r)) = f2b(h);
        }
      }
    __syncthreads();                          // h2 ready; mix2 zb reads done

    // ---------------- LAYER 3: sH[96][128] @ wB3 (n: u=0..2, z=3..5) ----------------
    f32x4 acc3 = zero4;
    if (wid < 6) {
      #pragma unroll
      for (int ch = 0; ch < 4; ++ch) {
        int r = wid * 16 + l15;
        bf16x8 a3 = *(const bf16x8*)(sHc + swz(r * 256 + ch * 64 + lk * 16, r));
        acc3 = __builtin_amdgcn_mfma_f32_16x16x32_bf16(a3, wB3[ch], acc3, 0, 0, 0);
      }
    }
    // z3 -> zb (stride 4)
    if (wid < 6 && l15 >= 3 && l15 < 6) {
      #pragma unroll
      for (int rg = 0; rg < 4; ++rg) {
        int r = wid * 16 + lk * 4 + rg;
        if (r < REAL_ROWS) zb[r * 4 + (l15 - 3)] = acc3[rg];
      }
    }
    __syncthreads();
    if (wid < 6 && l15 < 3) {
      #pragma unroll
      for (int rg = 0; rg < 4; ++rg) {
        int r = wid * 16 + lk * 4 + rg;
        if (r < REAL_ROWS) {
          float v = acc3[rg] + lmix(zb, 4, r, l15) + bias3;
          int e = r / 21;
          int n = r - e * 21;
          outp[((size_t)(gtile * TB + e) * N_JOINT + n) * 3 + l15] = v;
        }
      }
    }
    __syncthreads();   // zb/sH safe for next tile's writes; sA writes drained
  }
}

extern "C" void kernel_launch(void* const* d_in, const int* in_sizes, int n_in,
                              void* d_out, int out_size, void* d_ws, size_t ws_size,
                              hipStream_t stream) {
  const float* xp  = (const float*)d_in[0];
  const float* W1p = (const float*)d_in[1];
  const float* b1p = (const float*)d_in[2];
  const float* W2p = (const float*)d_in[3];
  const float* b2p = (const float*)d_in[4];
  const float* W3p = (const float*)d_in[5];
  const float* b3p = (const float*)d_in[6];
  uint16_t* ws = (uint16_t*)d_ws;

  hipLaunchKernelGGL(prep_weights, dim3(196), dim3(512), 0, stream, W1p, W2p, W3p, ws);

  const uint16_t* wf1 = ws;
  const uint16_t* wf2 = ws + 65536;
  const uint16_t* wf3 = ws + 65536 + 32768;
  hipLaunchKernelGGL(cheb3_main, dim3(NBLK), dim3(512), 0, stream,
                     xp, wf1, wf2, wf3, b1p, b2p, b3p, (float*)d_out);
}

// Round 4
// 1054.865 us; speedup vs baseline: 1.0266x; 1.0266x over previous
//
#include <hip/hip_runtime.h>
#include <stdint.h>

typedef __bf16 bf16x8 __attribute__((ext_vector_type(8)));
typedef float  f32x4  __attribute__((ext_vector_type(4)));

#define N_JOINT 21
#define TB 4
#define REAL_ROWS 84               // 21*4
#define RPAD 96                    // 6 MFMA M-tiles
#define BATCH 16384
#define TILES 8                    // tiles per block
#define NBLK (BATCH / (TB * TILES))   // 512 blocks
#define ZSTRIDE 129                // odd stride: bank = (r+c)%32, ~2-way

__device__ __forceinline__ uint32_t swz(uint32_t byteoff, uint32_t row) {
  return byteoff ^ ((row & 7u) << 4);
}
__device__ __forceinline__ uint16_t f2b(float v) {
  __bf16 b = (__bf16)v;
  return __builtin_bit_cast(uint16_t, b);
}

// (L z)[r][c], z in LDS row stride S floats. 21-joint hand tree.
__device__ __forceinline__ float lmix(const float* zbp, int S, int r, int c) {
  int e = r / 21;
  int n = r - e * 21;
  const float* rowb = zbp + e * 21 * S + c;
  float zv = rowb[n * S];
  float s = zv;
  float invd;
  if (n == 0) {
    s += rowb[1 * S] + rowb[5 * S] + rowb[9 * S] + rowb[13 * S] + rowb[17 * S];
    invd = 1.f / 6.f;
  } else {
    int p = (n - 1) & 3;
    if (p == 3) { s += rowb[(n - 1) * S]; invd = 0.5f; }
    else {
      int left = (p == 0) ? 0 : (n - 1);
      s += rowb[left * S] + rowb[(n + 1) * S];
      invd = 1.f / 3.f;
    }
  }
  return zv - invd * s;
}

__device__ __forceinline__ void mixone(char* sHc, const float* zbp, int r, int cu,
                                       float u, float bias) {
  float h = u + lmix(zbp, ZSTRIDE, r, cu) + bias;
  h = (h > 0.f) ? h : 0.01f * h;
  *(uint16_t*)(sHc + swz(r * 256 + cu * 2, r)) = f2b(h);
}

// ---------------- prep: fp32 weights -> bf16 frag-layout in ws ----------------
__global__ void prep_weights(const float* __restrict__ W1, const float* __restrict__ W2,
                             const float* __restrict__ W3, uint16_t* __restrict__ ws) {
  uint16_t* wf1 = ws;
  uint16_t* wf2 = ws + 65536;
  uint16_t* wf3 = ws + 65536 + 32768;
  for (int i = blockIdx.x * blockDim.x + threadIdx.x; i < 100352;
       i += gridDim.x * blockDim.x) {
    if (i < 65536) {
      int n = i >> 8, k = i & 255;
      float v = (n < 128) ? W1[k * 128 + n] : W1[32768 + k * 128 + (n - 128)];
      wf1[i] = f2b(v);
    } else if (i < 98304) {
      int j = i - 65536; int n = j >> 7, k = j & 127;
      float v = (n < 128) ? W2[k * 128 + n] : W2[16384 + k * 128 + (n - 128)];
      wf2[j] = f2b(v);
    } else {
      int j = i - 98304; int n = j >> 7, k = j & 127;
      float v = 0.f;
      if (n < 3)      v = W3[k * 3 + n];
      else if (n < 6) v = W3[384 + k * 3 + (n - 3)];
      wf3[j] = f2b(v);
    }
  }
}

// ------------- macros: everything individually named, no private arrays -------------
#define MFMA(d, va, vb) d = __builtin_amdgcn_mfma_f32_16x16x32_bf16(va, vb, d, 0, 0, 0)

#define LD_W1(ch) \
  w1_##ch##a = *(const bf16x8*)(wf1 + nu * 256 + ch * 32 + lk * 8); \
  w1_##ch##b = *(const bf16x8*)(wf1 + (nu + 128) * 256 + ch * 32 + lk * 8)
#define LD_W2(ch) \
  w2_##ch##a = *(const bf16x8*)(wf2 + nu * 128 + ch * 32 + lk * 8); \
  w2_##ch##b = *(const bf16x8*)(wf2 + (nu + 128) * 128 + ch * 32 + lk * 8)
#define LD_W3(ch) \
  w3_##ch = *(const bf16x8*)(wf3 + l15 * 128 + ch * 32 + lk * 8)

#define L1_CH(ch) { \
  const int kb_ = ch * 64 + lk * 16; \
  bf16x8 a0_ = *(const bf16x8*)(sAc + swz((0*16 + l15) * 512 + kb_, 0*16 + l15)); \
  bf16x8 a1_ = *(const bf16x8*)(sAc + swz((1*16 + l15) * 512 + kb_, 1*16 + l15)); \
  bf16x8 a2_ = *(const bf16x8*)(sAc + swz((2*16 + l15) * 512 + kb_, 2*16 + l15)); \
  bf16x8 a3_ = *(const bf16x8*)(sAc + swz((3*16 + l15) * 512 + kb_, 3*16 + l15)); \
  bf16x8 a4_ = *(const bf16x8*)(sAc + swz((4*16 + l15) * 512 + kb_, 4*16 + l15)); \
  bf16x8 a5_ = *(const bf16x8*)(sAc + swz((5*16 + l15) * 512 + kb_, 5*16 + l15)); \
  MFMA(u0, a0_, w1_##ch##a); MFMA(u1, a1_, w1_##ch##a); MFMA(u2, a2_, w1_##ch##a); \
  MFMA(u3, a3_, w1_##ch##a); MFMA(u4, a4_, w1_##ch##a); MFMA(u5, a5_, w1_##ch##a); \
  MFMA(z0, a0_, w1_##ch##b); MFMA(z1, a1_, w1_##ch##b); MFMA(z2, a2_, w1_##ch##b); \
  MFMA(z3, a3_, w1_##ch##b); MFMA(z4, a4_, w1_##ch##b); MFMA(z5, a5_, w1_##ch##b); \
}

#define L2_CH(ch) { \
  const int kb_ = ch * 64 + lk * 16; \
  bf16x8 a0_ = *(const bf16x8*)(sHc + swz((0*16 + l15) * 256 + kb_, 0*16 + l15)); \
  bf16x8 a1_ = *(const bf16x8*)(sHc + swz((1*16 + l15) * 256 + kb_, 1*16 + l15)); \
  bf16x8 a2_ = *(const bf16x8*)(sHc + swz((2*16 + l15) * 256 + kb_, 2*16 + l15)); \
  bf16x8 a3_ = *(const bf16x8*)(sHc + swz((3*16 + l15) * 256 + kb_, 3*16 + l15)); \
  bf16x8 a4_ = *(const bf16x8*)(sHc + swz((4*16 + l15) * 256 + kb_, 4*16 + l15)); \
  bf16x8 a5_ = *(const bf16x8*)(sHc + swz((5*16 + l15) * 256 + kb_, 5*16 + l15)); \
  MFMA(u0, a0_, w2_##ch##a); MFMA(u1, a1_, w2_##ch##a); MFMA(u2, a2_, w2_##ch##a); \
  MFMA(u3, a3_, w2_##ch##a); MFMA(u4, a4_, w2_##ch##a); MFMA(u5, a5_, w2_##ch##a); \
  MFMA(z0, a0_, w2_##ch##b); MFMA(z1, a1_, w2_##ch##b); MFMA(z2, a2_, w2_##ch##b); \
  MFMA(z3, a3_, w2_##ch##b); MFMA(z4, a4_, w2_##ch##b); MFMA(z5, a5_, w2_##ch##b); \
}

#define L3_CH(ch) { \
  bf16x8 a3_ = *(const bf16x8*)(sHc + swz((wid * 16 + l15) * 256 + ch * 64 + lk * 16, wid * 16 + l15)); \
  MFMA(c3, a3_, w3_##ch); \
}

#define ZST4(mt, v) { \
  const int rb_ = mt * 16 + lk * 4; \
  zb[(rb_ + 0) * ZSTRIDE + cu] = v[0]; \
  zb[(rb_ + 1) * ZSTRIDE + cu] = v[1]; \
  zb[(rb_ + 2) * ZSTRIDE + cu] = v[2]; \
  zb[(rb_ + 3) * ZSTRIDE + cu] = v[3]; \
}
#define ZST4G(mt, v) { \
  const int rb_ = mt * 16 + lk * 4; \
  if (rb_ + 0 < REAL_ROWS) zb[(rb_ + 0) * ZSTRIDE + cu] = v[0]; \
  if (rb_ + 1 < REAL_ROWS) zb[(rb_ + 1) * ZSTRIDE + cu] = v[1]; \
  if (rb_ + 2 < REAL_ROWS) zb[(rb_ + 2) * ZSTRIDE + cu] = v[2]; \
  if (rb_ + 3 < REAL_ROWS) zb[(rb_ + 3) * ZSTRIDE + cu] = v[3]; \
}
#define MIX4(mt, v, bias) { \
  const int rb_ = mt * 16 + lk * 4; \
  mixone(sHc, zb, rb_ + 0, cu, v[0], bias); \
  mixone(sHc, zb, rb_ + 1, cu, v[1], bias); \
  mixone(sHc, zb, rb_ + 2, cu, v[2], bias); \
  mixone(sHc, zb, rb_ + 3, cu, v[3], bias); \
}
#define MIX4G(mt, v, bias) { \
  const int rb_ = mt * 16 + lk * 4; \
  if (rb_ + 0 < REAL_ROWS) mixone(sHc, zb, rb_ + 0, cu, v[0], bias); \
  if (rb_ + 1 < REAL_ROWS) mixone(sHc, zb, rb_ + 1, cu, v[1], bias); \
  if (rb_ + 2 < REAL_ROWS) mixone(sHc, zb, rb_ + 2, cu, v[2], bias); \
  if (rb_ + 3 < REAL_ROWS) mixone(sHc, zb, rb_ + 3, cu, v[3], bias); \
}

#define PF_ISSUE(p0, p1, j, src) { \
  const int i_ = tid + j * 512; \
  const int r_ = i_ >> 5, c8_ = (i_ & 31) * 8; \
  p0 = *(const float4*)(src + r_ * 256 + c8_); \
  p1 = *(const float4*)(src + r_ * 256 + c8_ + 4); \
}
#define PF_ISSUE_G(p0, p1, j, src) { \
  const int i_ = tid + j * 512; \
  if (i_ < 2688) { \
    const int r_ = i_ >> 5, c8_ = (i_ & 31) * 8; \
    p0 = *(const float4*)(src + r_ * 256 + c8_); \
    p1 = *(const float4*)(src + r_ * 256 + c8_ + 4); \
  } \
}
#define PF_WRITE(p0, p1, j) { \
  const int i_ = tid + j * 512; \
  const int r_ = i_ >> 5, c8_ = (i_ & 31) * 8; \
  bf16x8 o_; \
  o_[0] = (__bf16)p0.x; o_[1] = (__bf16)p0.y; o_[2] = (__bf16)p0.z; o_[3] = (__bf16)p0.w; \
  o_[4] = (__bf16)p1.x; o_[5] = (__bf16)p1.y; o_[6] = (__bf16)p1.z; o_[7] = (__bf16)p1.w; \
  *(bf16x8*)(sAc + swz(r_ * 512 + c8_ * 2, r_)) = o_; \
}
#define PF_WRITE_G(p0, p1, j) { \
  const int i_ = tid + j * 512; \
  if (i_ < 2688) { \
    const int r_ = i_ >> 5, c8_ = (i_ & 31) * 8; \
    bf16x8 o_; \
    o_[0] = (__bf16)p0.x; o_[1] = (__bf16)p0.y; o_[2] = (__bf16)p0.z; o_[3] = (__bf16)p0.w; \
    o_[4] = (__bf16)p1.x; o_[5] = (__bf16)p1.y; o_[6] = (__bf16)p1.z; o_[7] = (__bf16)p1.w; \
    *(bf16x8*)(sAc + swz(r_ * 512 + c8_ * 2, r_)) = o_; \
  } \
}

// ---------------- fused main ----------------
// Register budget forced via amdgpu attrs: waves_per_eu(1,2) -> allocator may use
// up to 512 VGPRs (LDS already caps occupancy at 1 block/CU = 2 waves/EU).
// R2/R3 lesson: __launch_bounds__ alone left VGPR_Count=128 + 583MB scratch spill.
__global__ __attribute__((amdgpu_flat_work_group_size(512, 512)))
           __attribute__((amdgpu_waves_per_eu(1, 2)))
void cheb3_main(const float* __restrict__ xp,
                const uint16_t* __restrict__ wf1, const uint16_t* __restrict__ wf2,
                const uint16_t* __restrict__ wf3,
                const float* __restrict__ b1p, const float* __restrict__ b2p,
                const float* __restrict__ b3p, float* __restrict__ outp)
{
  __shared__ __align__(16) uint16_t sA[RPAD * 256];   // x bf16, swizzled (48 KB)
  __shared__ __align__(16) uint16_t sH[RPAD * 128];   // h bf16, swizzled (24 KB)
  __shared__ float zb[REAL_ROWS * ZSTRIDE];           // z fp32 (42.4 KB)

  const int tid  = threadIdx.x;
  const int wid  = tid >> 6;
  const int lane = tid & 63;
  const int l15  = lane & 15;
  const int lk   = lane >> 4;
  char* sAc = (char*)sA;
  char* sHc = (char*)sH;

  const int nu = wid * 16 + l15;

  // persistent B-fragments: 28 named bf16x8 (112 VGPRs)
  bf16x8 w1_0a, w1_0b, w1_1a, w1_1b, w1_2a, w1_2b, w1_3a, w1_3b,
         w1_4a, w1_4b, w1_5a, w1_5b, w1_6a, w1_6b, w1_7a, w1_7b;
  bf16x8 w2_0a, w2_0b, w2_1a, w2_1b, w2_2a, w2_2b, w2_3a, w2_3b;
  bf16x8 w3_0, w3_1, w3_2, w3_3;
  LD_W1(0); LD_W1(1); LD_W1(2); LD_W1(3); LD_W1(4); LD_W1(5); LD_W1(6); LD_W1(7);
  LD_W2(0); LD_W2(1); LD_W2(2); LD_W2(3);
  LD_W3(0); LD_W3(1); LD_W3(2); LD_W3(3);

  const int   cu    = nu;
  const float bias1 = b1p[cu];
  const float bias2 = b2p[cu];
  const float bias3 = (l15 < 3) ? b3p[l15] : 0.f;

  // zero pad rows 84..95 (written once)
  {
    uint4 z16 = make_uint4(0, 0, 0, 0);
    for (int i = tid; i < (12 * 256) / 8; i += 512) {
      int f0 = i * 8, r = 84 + (f0 >> 8), c = f0 & 255;
      *(uint4*)(sAc + swz(r * 512 + c * 2, r)) = z16;
    }
    for (int i = tid; i < (12 * 128) / 8; i += 512) {
      int f0 = i * 8, r = 84 + (f0 >> 7), c = f0 & 127;
      *(uint4*)(sHc + swz(r * 256 + c * 2, r)) = z16;
    }
  }

  // stage tile 0 synchronously
  {
    const float* xg = xp + (size_t)(blockIdx.x * TILES) * (TB * N_JOINT * 256);
    #pragma unroll
    for (int j = 0; j < 6; ++j) {
      int i = tid + j * 512;
      if (i < 2688) {
        int r = i >> 5, c8 = (i & 31) * 8;
        float4 v0 = *(const float4*)(xg + r * 256 + c8);
        float4 v1 = *(const float4*)(xg + r * 256 + c8 + 4);
        bf16x8 o;
        o[0] = (__bf16)v0.x; o[1] = (__bf16)v0.y; o[2] = (__bf16)v0.z; o[3] = (__bf16)v0.w;
        o[4] = (__bf16)v1.x; o[5] = (__bf16)v1.y; o[6] = (__bf16)v1.z; o[7] = (__bf16)v1.w;
        *(bf16x8*)(sAc + swz(r * 512 + c8 * 2, r)) = o;
      }
    }
  }
  __syncthreads();

  const f32x4 zero4 = {0.f, 0.f, 0.f, 0.f};

  for (int t = 0; t < TILES; ++t) {
    const int gtile = blockIdx.x * TILES + t;
    const bool pf = (t + 1 < TILES);
    const float* xn = xp + (size_t)(gtile + 1) * (TB * N_JOINT * 256);

    // ---------------- LAYER 1 ----------------
    f32x4 u0 = zero4, u1 = zero4, u2 = zero4, u3 = zero4, u4 = zero4, u5 = zero4;
    f32x4 z0 = zero4, z1 = zero4, z2 = zero4, z3 = zero4, z4 = zero4, z5 = zero4;
    L1_CH(0); L1_CH(1); L1_CH(2); L1_CH(3); L1_CH(4); L1_CH(5); L1_CH(6); L1_CH(7);

    float4 pA0, pA1, pA2, pA3, pA4, pA5;
    if (pf) { PF_ISSUE(pA0, pA1, 0, xn); PF_ISSUE(pA2, pA3, 1, xn); PF_ISSUE(pA4, pA5, 2, xn); }

    ZST4(0, z0); ZST4(1, z1); ZST4(2, z2); ZST4(3, z3); ZST4(4, z4); ZST4G(5, z5);
    __syncthreads();                          // z1 visible; L1 sA reads done

    float4 pB0, pB1, pB2, pB3, pB4, pB5;
    if (pf) {
      PF_WRITE(pA0, pA1, 0); PF_WRITE(pA2, pA3, 1); PF_WRITE(pA4, pA5, 2);
      PF_ISSUE(pB0, pB1, 3, xn); PF_ISSUE(pB2, pB3, 4, xn); PF_ISSUE_G(pB4, pB5, 5, xn);
    }

    MIX4(0, u0, bias1); MIX4(1, u1, bias1); MIX4(2, u2, bias1);
    MIX4(3, u3, bias1); MIX4(4, u4, bias1); MIX4G(5, u5, bias1);
    __syncthreads();                          // sH (h1) ready

    // ---------------- LAYER 2 ----------------
    u0 = zero4; u1 = zero4; u2 = zero4; u3 = zero4; u4 = zero4; u5 = zero4;
    z0 = zero4; z1 = zero4; z2 = zero4; z3 = zero4; z4 = zero4; z5 = zero4;
    L2_CH(0); L2_CH(1); L2_CH(2); L2_CH(3);

    ZST4(0, z0); ZST4(1, z1); ZST4(2, z2); ZST4(3, z3); ZST4(4, z4); ZST4G(5, z5);
    if (pf) { PF_WRITE(pB0, pB1, 3); PF_WRITE(pB2, pB3, 4); PF_WRITE_G(pB4, pB5, 5); }
    __syncthreads();                          // z2 visible; L2 sH reads done

    MIX4(0, u0, bias2); MIX4(1, u1, bias2); MIX4(2, u2, bias2);
    MIX4(3, u3, bias2); MIX4(4, u4, bias2); MIX4G(5, u5, bias2);
    __syncthreads();                          // sH (h2) ready

    // ---------------- LAYER 3 ----------------
    f32x4 c3 = zero4;
    if (wid < 6) { L3_CH(0); L3_CH(1); L3_CH(2); L3_CH(3); }
    if (wid < 6 && l15 >= 3 && l15 < 6) {
      const int rb_ = wid * 16 + lk * 4;
      if (rb_ + 0 < REAL_ROWS) zb[(rb_ + 0) * 4 + (l15 - 3)] = c3[0];
      if (rb_ + 1 < REAL_ROWS) zb[(rb_ + 1) * 4 + (l15 - 3)] = c3[1];
      if (rb_ + 2 < REAL_ROWS) zb[(rb_ + 2) * 4 + (l15 - 3)] = c3[2];
      if (rb_ + 3 < REAL_ROWS) zb[(rb_ + 3) * 4 + (l15 - 3)] = c3[3];
    }
    __syncthreads();
    if (wid < 6 && l15 < 3) {
      const int rb_ = wid * 16 + lk * 4;
      #define OUT1(rg) { \
        int r = rb_ + rg; \
        if (r < REAL_ROWS) { \
          float v = c3[rg] + lmix(zb, 4, r, l15) + bias3; \
          int e = r / 21, n = r - e * 21; \
          outp[((size_t)(gtile * TB + e) * N_JOINT + n) * 3 + l15] = v; \
        } \
      }
      OUT1(0); OUT1(1); OUT1(2); OUT1(3);
      #undef OUT1
    }
    __syncthreads();   // zb/sH safe for next tile; sA writes drained
  }
}

extern "C" void kernel_launch(void* const* d_in, const int* in_sizes, int n_in,
                              void* d_out, int out_size, void* d_ws, size_t ws_size,
                              hipStream_t stream) {
  const float* xp  = (const float*)d_in[0];
  const float* W1p = (const float*)d_in[1];
  const float* b1p = (const float*)d_in[2];
  const float* W2p = (const float*)d_in[3];
  const float* b2p = (const float*)d_in[4];
  const float* W3p = (const float*)d_in[5];
  const float* b3p = (const float*)d_in[6];
  uint16_t* ws = (uint16_t*)d_ws;

  hipLaunchKernelGGL(prep_weights, dim3(196), dim3(512), 0, stream, W1p, W2p, W3p, ws);

  const uint16_t* wf1 = ws;
  const uint16_t* wf2 = ws + 65536;
  const uint16_t* wf3 = ws + 65536 + 32768;
  hipLaunchKernelGGL(cheb3_main, dim3(NBLK), dim3(512), 0, stream,
                     xp, wf1, wf2, wf3, b1p, b2p, b3p, (float*)d_out);
}

// Round 5
// 466.388 us; speedup vs baseline: 2.3219x; 2.2618x over previous
//
#include <hip/hip_runtime.h>
#include <stdint.h>

typedef __bf16 bf16x8 __attribute__((ext_vector_type(8)));
typedef float  f32x4  __attribute__((ext_vector_type(4)));

#define N_JOINT 21
#define TB 4
#define REAL_ROWS 84               // 21*4
#define RPAD 96                    // 6 MFMA M-tiles
#define BATCH 16384
#define TILES 16                   // tiles per block
#define NBLK (BATCH / (TB * TILES))   // 256 blocks = 1 per CU
#define ZSTRIDE 129                // odd stride: bank = (r+c)%32

__device__ __forceinline__ uint32_t swz(uint32_t byteoff, uint32_t row) {
  return byteoff ^ ((row & 7u) << 4);
}
__device__ __forceinline__ uint16_t f2b(float v) {
  __bf16 b = (__bf16)v;
  return __builtin_bit_cast(uint16_t, b);
}

// (L z)[r][c], z in LDS row stride S floats. 21-joint hand tree.
__device__ __forceinline__ float lmix(const float* zbp, int S, int r, int c) {
  int e = r / 21;
  int n = r - e * 21;
  const float* rowb = zbp + e * 21 * S + c;
  float zv = rowb[n * S];
  float s = zv;
  float invd;
  if (n == 0) {
    s += rowb[1 * S] + rowb[5 * S] + rowb[9 * S] + rowb[13 * S] + rowb[17 * S];
    invd = 1.f / 6.f;
  } else {
    int p = (n - 1) & 3;
    if (p == 3) { s += rowb[(n - 1) * S]; invd = 0.5f; }
    else {
      int left = (p == 0) ? 0 : (n - 1);
      s += rowb[left * S] + rowb[(n + 1) * S];
      invd = 1.f / 3.f;
    }
  }
  return zv - invd * s;
}

__device__ __forceinline__ void mixone(char* sHc, const float* zbp, int r, int cu,
                                       float u, float bias) {
  float h = u + lmix(zbp, ZSTRIDE, r, cu) + bias;
  h = (h > 0.f) ? h : 0.01f * h;
  *(uint16_t*)(sHc + swz(r * 256 + cu * 2, r)) = f2b(h);
}

// ---------------- prep: fp32 weights -> bf16 frag-layout in ws ----------------
// wf1[256][256] (row n = concat(k0-half, k1-half) of Cout, k contiguous),
// wf2[256][128], wf3[16][128]
__global__ void prep_weights(const float* __restrict__ W1, const float* __restrict__ W2,
                             const float* __restrict__ W3, uint16_t* __restrict__ ws) {
  uint16_t* wf1 = ws;
  uint16_t* wf2 = ws + 65536;
  uint16_t* wf3 = ws + 65536 + 32768;
  for (int i = blockIdx.x * blockDim.x + threadIdx.x; i < 100352;
       i += gridDim.x * blockDim.x) {
    if (i < 65536) {
      int n = i >> 8, k = i & 255;
      float v = (n < 128) ? W1[k * 128 + n] : W1[32768 + k * 128 + (n - 128)];
      wf1[i] = f2b(v);
    } else if (i < 98304) {
      int j = i - 65536; int n = j >> 7, k = j & 127;
      float v = (n < 128) ? W2[k * 128 + n] : W2[16384 + k * 128 + (n - 128)];
      wf2[j] = f2b(v);
    } else {
      int j = i - 98304; int n = j >> 7, k = j & 127;
      float v = 0.f;
      if (n < 3)      v = W3[k * 3 + n];
      else if (n < 6) v = W3[384 + k * 3 + (n - 3)];
      wf3[j] = f2b(v);
    }
  }
}

#define MFMA(d, va, vb) d = __builtin_amdgcn_mfma_f32_16x16x32_bf16(va, vb, d, 0, 0, 0)

#define ZST4(mt, v) { \
  const int rb_ = mt * 16 + lk * 4; \
  zb[(rb_ + 0) * ZSTRIDE + cu] = v[0]; \
  zb[(rb_ + 1) * ZSTRIDE + cu] = v[1]; \
  zb[(rb_ + 2) * ZSTRIDE + cu] = v[2]; \
  zb[(rb_ + 3) * ZSTRIDE + cu] = v[3]; \
}
#define ZST4G(mt, v) { \
  const int rb_ = mt * 16 + lk * 4; \
  if (rb_ + 0 < REAL_ROWS) zb[(rb_ + 0) * ZSTRIDE + cu] = v[0]; \
  if (rb_ + 1 < REAL_ROWS) zb[(rb_ + 1) * ZSTRIDE + cu] = v[1]; \
  if (rb_ + 2 < REAL_ROWS) zb[(rb_ + 2) * ZSTRIDE + cu] = v[2]; \
  if (rb_ + 3 < REAL_ROWS) zb[(rb_ + 3) * ZSTRIDE + cu] = v[3]; \
}
#define MIX4(mt, v, bias) { \
  const int rb_ = mt * 16 + lk * 4; \
  mixone(sHc, zb, rb_ + 0, cu, v[0], bias); \
  mixone(sHc, zb, rb_ + 1, cu, v[1], bias); \
  mixone(sHc, zb, rb_ + 2, cu, v[2], bias); \
  mixone(sHc, zb, rb_ + 3, cu, v[3], bias); \
}
#define MIX4G(mt, v, bias) { \
  const int rb_ = mt * 16 + lk * 4; \
  if (rb_ + 0 < REAL_ROWS) mixone(sHc, zb, rb_ + 0, cu, v[0], bias); \
  if (rb_ + 1 < REAL_ROWS) mixone(sHc, zb, rb_ + 1, cu, v[1], bias); \
  if (rb_ + 2 < REAL_ROWS) mixone(sHc, zb, rb_ + 2, cu, v[2], bias); \
  if (rb_ + 3 < REAL_ROWS) mixone(sHc, zb, rb_ + 3, cu, v[3], bias); \
}

#define PF_ISSUE(p0, p1, j, src) { \
  const int i_ = tid + j * 512; \
  const int r_ = i_ >> 5, c8_ = (i_ & 31) * 8; \
  p0 = *(const float4*)(src + r_ * 256 + c8_); \
  p1 = *(const float4*)(src + r_ * 256 + c8_ + 4); \
}
#define PF_ISSUE_G(p0, p1, j, src) { \
  const int i_ = tid + j * 512; \
  if (i_ < 2688) { \
    const int r_ = i_ >> 5, c8_ = (i_ & 31) * 8; \
    p0 = *(const float4*)(src + r_ * 256 + c8_); \
    p1 = *(const float4*)(src + r_ * 256 + c8_ + 4); \
  } \
}
#define PF_WRITE(p0, p1, j) { \
  const int i_ = tid + j * 512; \
  const int r_ = i_ >> 5, c8_ = (i_ & 31) * 8; \
  bf16x8 o_; \
  o_[0] = (__bf16)p0.x; o_[1] = (__bf16)p0.y; o_[2] = (__bf16)p0.z; o_[3] = (__bf16)p0.w; \
  o_[4] = (__bf16)p1.x; o_[5] = (__bf16)p1.y; o_[6] = (__bf16)p1.z; o_[7] = (__bf16)p1.w; \
  *(bf16x8*)(sAc + swz(r_ * 512 + c8_ * 2, r_)) = o_; \
}
#define PF_WRITE_G(p0, p1, j) { \
  const int i_ = tid + j * 512; \
  if (i_ < 2688) { \
    const int r_ = i_ >> 5, c8_ = (i_ & 31) * 8; \
    bf16x8 o_; \
    o_[0] = (__bf16)p0.x; o_[1] = (__bf16)p0.y; o_[2] = (__bf16)p0.z; o_[3] = (__bf16)p0.w; \
    o_[4] = (__bf16)p1.x; o_[5] = (__bf16)p1.y; o_[6] = (__bf16)p1.z; o_[7] = (__bf16)p1.w; \
    *(bf16x8*)(sAc + swz(r_ * 512 + c8_ * 2, r_)) = o_; \
  } \
}

// ---------------- fused main ----------------
// R2-R4 lesson: allocator pins this kernel at 128 VGPRs regardless of launch
// bounds/attrs -> persistent weight registers (112 VGPR) always spilled to
// scratch (475-583 MB). Fix: weights are streamed from L2 per chunk (load ->
// MFMA -> discard, 8 VGPR transient). ws layout is fragment-exact so each
// load is one dwordx4 pair. #pragma unroll 1 prevents load hoisting from
// recreating the pressure.
__global__ __launch_bounds__(512)
void cheb3_main(const float* __restrict__ xp,
                const uint16_t* __restrict__ wf1, const uint16_t* __restrict__ wf2,
                const uint16_t* __restrict__ wf3,
                const float* __restrict__ b1p, const float* __restrict__ b2p,
                const float* __restrict__ b3p, float* __restrict__ outp)
{
  __shared__ __align__(16) uint16_t sA[RPAD * 256];   // x bf16, swizzled (48 KB)
  __shared__ __align__(16) uint16_t sH[RPAD * 128];   // h bf16, swizzled (24 KB)
  __shared__ float zb[REAL_ROWS * ZSTRIDE];           // z fp32 (42.4 KB)

  const int tid  = threadIdx.x;
  const int wid  = tid >> 6;
  const int lane = tid & 63;
  const int l15  = lane & 15;
  const int lk   = lane >> 4;
  char* sAc = (char*)sA;
  char* sHc = (char*)sH;

  const int nu = wid * 16 + l15;     // this wave's u-column block
  const int cu = nu;
  const float bias1 = b1p[cu];
  const float bias2 = b2p[cu];
  const float bias3 = (l15 < 3) ? b3p[l15] : 0.f;

  // zero pad rows 84..95 (written once)
  {
    uint4 z16 = make_uint4(0, 0, 0, 0);
    for (int i = tid; i < (12 * 256) / 8; i += 512) {
      int f0 = i * 8, r = 84 + (f0 >> 8), c = f0 & 255;
      *(uint4*)(sAc + swz(r * 512 + c * 2, r)) = z16;
    }
    for (int i = tid; i < (12 * 128) / 8; i += 512) {
      int f0 = i * 8, r = 84 + (f0 >> 7), c = f0 & 127;
      *(uint4*)(sHc + swz(r * 256 + c * 2, r)) = z16;
    }
  }

  // stage tile 0 synchronously
  {
    const float* xg = xp + (size_t)(blockIdx.x * TILES) * (TB * N_JOINT * 256);
    #pragma unroll
    for (int j = 0; j < 6; ++j) {
      int i = tid + j * 512;
      if (i < 2688) {
        int r = i >> 5, c8 = (i & 31) * 8;
        float4 v0 = *(const float4*)(xg + r * 256 + c8);
        float4 v1 = *(const float4*)(xg + r * 256 + c8 + 4);
        bf16x8 o;
        o[0] = (__bf16)v0.x; o[1] = (__bf16)v0.y; o[2] = (__bf16)v0.z; o[3] = (__bf16)v0.w;
        o[4] = (__bf16)v1.x; o[5] = (__bf16)v1.y; o[6] = (__bf16)v1.z; o[7] = (__bf16)v1.w;
        *(bf16x8*)(sAc + swz(r * 512 + c8 * 2, r)) = o;
      }
    }
  }
  __syncthreads();

  const f32x4 zero4 = {0.f, 0.f, 0.f, 0.f};

  for (int t = 0; t < TILES; ++t) {
    const int gtile = blockIdx.x * TILES + t;
    const bool pf = (t + 1 < TILES);
    const float* xn = xp + (size_t)(gtile + 1) * (TB * N_JOINT * 256);

    // ---------------- LAYER 1: sA[96][256] @ W1frag ----------------
    f32x4 u0 = zero4, u1 = zero4, u2 = zero4, u3 = zero4, u4 = zero4, u5 = zero4;
    f32x4 z0 = zero4, z1 = zero4, z2 = zero4, z3 = zero4, z4 = zero4, z5 = zero4;
    #pragma unroll 1
    for (int ch = 0; ch < 8; ++ch) {
      const bf16x8 wa_ = *(const bf16x8*)(wf1 + nu * 256 + ch * 32 + lk * 8);
      const bf16x8 wb_ = *(const bf16x8*)(wf1 + (nu + 128) * 256 + ch * 32 + lk * 8);
      const int kb_ = ch * 64 + lk * 16;
      bf16x8 a0_ = *(const bf16x8*)(sAc + swz((0*16 + l15) * 512 + kb_, 0*16 + l15));
      bf16x8 a1_ = *(const bf16x8*)(sAc + swz((1*16 + l15) * 512 + kb_, 1*16 + l15));
      bf16x8 a2_ = *(const bf16x8*)(sAc + swz((2*16 + l15) * 512 + kb_, 2*16 + l15));
      bf16x8 a3_ = *(const bf16x8*)(sAc + swz((3*16 + l15) * 512 + kb_, 3*16 + l15));
      bf16x8 a4_ = *(const bf16x8*)(sAc + swz((4*16 + l15) * 512 + kb_, 4*16 + l15));
      bf16x8 a5_ = *(const bf16x8*)(sAc + swz((5*16 + l15) * 512 + kb_, 5*16 + l15));
      MFMA(u0, a0_, wa_); MFMA(u1, a1_, wa_); MFMA(u2, a2_, wa_);
      MFMA(u3, a3_, wa_); MFMA(u4, a4_, wa_); MFMA(u5, a5_, wa_);
      MFMA(z0, a0_, wb_); MFMA(z1, a1_, wb_); MFMA(z2, a2_, wb_);
      MFMA(z3, a3_, wb_); MFMA(z4, a4_, wb_); MFMA(z5, a5_, wb_);
    }

    float4 pA0, pA1, pA2, pA3, pA4, pA5;
    if (pf) { PF_ISSUE(pA0, pA1, 0, xn); PF_ISSUE(pA2, pA3, 1, xn); PF_ISSUE(pA4, pA5, 2, xn); }

    ZST4(0, z0); ZST4(1, z1); ZST4(2, z2); ZST4(3, z3); ZST4(4, z4); ZST4G(5, z5);
    __syncthreads();                          // z1 visible; L1 sA reads done

    float4 pB0, pB1, pB2, pB3, pB4, pB5;
    if (pf) {
      PF_WRITE(pA0, pA1, 0); PF_WRITE(pA2, pA3, 1); PF_WRITE(pA4, pA5, 2);
      PF_ISSUE(pB0, pB1, 3, xn); PF_ISSUE(pB2, pB3, 4, xn); PF_ISSUE_G(pB4, pB5, 5, xn);
    }

    MIX4(0, u0, bias1); MIX4(1, u1, bias1); MIX4(2, u2, bias1);
    MIX4(3, u3, bias1); MIX4(4, u4, bias1); MIX4G(5, u5, bias1);
    __syncthreads();                          // sH (h1) ready

    // ---------------- LAYER 2: sH[96][128] @ W2frag ----------------
    u0 = zero4; u1 = zero4; u2 = zero4; u3 = zero4; u4 = zero4; u5 = zero4;
    z0 = zero4; z1 = zero4; z2 = zero4; z3 = zero4; z4 = zero4; z5 = zero4;
    #pragma unroll 1
    for (int ch = 0; ch < 4; ++ch) {
      const bf16x8 wa_ = *(const bf16x8*)(wf2 + nu * 128 + ch * 32 + lk * 8);
      const bf16x8 wb_ = *(const bf16x8*)(wf2 + (nu + 128) * 128 + ch * 32 + lk * 8);
      const int kb_ = ch * 64 + lk * 16;
      bf16x8 a0_ = *(const bf16x8*)(sHc + swz((0*16 + l15) * 256 + kb_, 0*16 + l15));
      bf16x8 a1_ = *(const bf16x8*)(sHc + swz((1*16 + l15) * 256 + kb_, 1*16 + l15));
      bf16x8 a2_ = *(const bf16x8*)(sHc + swz((2*16 + l15) * 256 + kb_, 2*16 + l15));
      bf16x8 a3_ = *(const bf16x8*)(sHc + swz((3*16 + l15) * 256 + kb_, 3*16 + l15));
      bf16x8 a4_ = *(const bf16x8*)(sHc + swz((4*16 + l15) * 256 + kb_, 4*16 + l15));
      bf16x8 a5_ = *(const bf16x8*)(sHc + swz((5*16 + l15) * 256 + kb_, 5*16 + l15));
      MFMA(u0, a0_, wa_); MFMA(u1, a1_, wa_); MFMA(u2, a2_, wa_);
      MFMA(u3, a3_, wa_); MFMA(u4, a4_, wa_); MFMA(u5, a5_, wa_);
      MFMA(z0, a0_, wb_); MFMA(z1, a1_, wb_); MFMA(z2, a2_, wb_);
      MFMA(z3, a3_, wb_); MFMA(z4, a4_, wb_); MFMA(z5, a5_, wb_);
    }

    ZST4(0, z0); ZST4(1, z1); ZST4(2, z2); ZST4(3, z3); ZST4(4, z4); ZST4G(5, z5);
    if (pf) { PF_WRITE(pB0, pB1, 3); PF_WRITE(pB2, pB3, 4); PF_WRITE_G(pB4, pB5, 5); }
    __syncthreads();                          // z2 visible; L2 sH reads done

    MIX4(0, u0, bias2); MIX4(1, u1, bias2); MIX4(2, u2, bias2);
    MIX4(3, u3, bias2); MIX4(4, u4, bias2); MIX4G(5, u5, bias2);
    __syncthreads();                          // sH (h2) ready

    // ---------------- LAYER 3: sH[96][128] @ W3frag ----------------
    f32x4 c3 = zero4;
    if (wid < 6) {
      #pragma unroll 1
      for (int ch = 0; ch < 4; ++ch) {
        const bf16x8 w3_ = *(const bf16x8*)(wf3 + l15 * 128 + ch * 32 + lk * 8);
        bf16x8 a3_ = *(const bf16x8*)(sHc + swz((wid * 16 + l15) * 256 + ch * 64 + lk * 16, wid * 16 + l15));
        MFMA(c3, a3_, w3_);
      }
    }
    if (wid < 6 && l15 >= 3 && l15 < 6) {
      const int rb_ = wid * 16 + lk * 4;
      if (rb_ + 0 < REAL_ROWS) zb[(rb_ + 0) * 4 + (l15 - 3)] = c3[0];
      if (rb_ + 1 < REAL_ROWS) zb[(rb_ + 1) * 4 + (l15 - 3)] = c3[1];
      if (rb_ + 2 < REAL_ROWS) zb[(rb_ + 2) * 4 + (l15 - 3)] = c3[2];
      if (rb_ + 3 < REAL_ROWS) zb[(rb_ + 3) * 4 + (l15 - 3)] = c3[3];
    }
    __syncthreads();
    if (wid < 6 && l15 < 3) {
      const int rb_ = wid * 16 + lk * 4;
      #define OUT1(rg) { \
        int r = rb_ + rg; \
        if (r < REAL_ROWS) { \
          float v = c3[rg] + lmix(zb, 4, r, l15) + bias3; \
          int e = r / 21, n = r - e * 21; \
          outp[((size_t)(gtile * TB + e) * N_JOINT + n) * 3 + l15] = v; \
        } \
      }
      OUT1(0); OUT1(1); OUT1(2); OUT1(3);
      #undef OUT1
    }
    __syncthreads();   // zb/sH safe for next tile; sA writes drained
  }
}

extern "C" void kernel_launch(void* const* d_in, const int* in_sizes, int n_in,
                              void* d_out, int out_size, void* d_ws, size_t ws_size,
                              hipStream_t stream) {
  const float* xp  = (const float*)d_in[0];
  const float* W1p = (const float*)d_in[1];
  const float* b1p = (const float*)d_in[2];
  const float* W2p = (const float*)d_in[3];
  const float* b2p = (const float*)d_in[4];
  const float* W3p = (const float*)d_in[5];
  const float* b3p = (const float*)d_in[6];
  uint16_t* ws = (uint16_t*)d_ws;

  hipLaunchKernelGGL(prep_weights, dim3(196), dim3(512), 0, stream, W1p, W2p, W3p, ws);

  const uint16_t* wf1 = ws;
  const uint16_t* wf2 = ws + 65536;
  const uint16_t* wf3 = ws + 65536 + 32768;
  hipLaunchKernelGGL(cheb3_main, dim3(NBLK), dim3(512), 0, stream,
                     xp, wf1, wf2, wf3, b1p, b2p, b3p, (float*)d_out);
}

// Round 6
// 327.720 us; speedup vs baseline: 3.3044x; 1.4231x over previous
//
#include <hip/hip_runtime.h>
#include <stdint.h>

typedef __bf16 bf16x8 __attribute__((ext_vector_type(8)));
typedef float  f32x4  __attribute__((ext_vector_type(4)));

#define N_JOINT 21
#define TB 2
#define REAL_ROWS 42               // 21*2
#define RPAD 48                    // 3 MFMA M-tiles
#define BATCH 16384
#define TILES 16                   // tiles per block
#define NBLK (BATCH / (TB * TILES))   // 512 blocks = 2 per CU
#define ZSTRIDE 129                // odd stride: bank = (r+c)%32
#define Z3OFF (REAL_ROWS * ZSTRIDE)   // disjoint z3 region (allows dropping a barrier)

__device__ __forceinline__ uint32_t swz(uint32_t byteoff, uint32_t row) {
  return byteoff ^ ((row & 7u) << 4);
}
__device__ __forceinline__ uint16_t f2b(float v) {
  __bf16 b = (__bf16)v;
  return __builtin_bit_cast(uint16_t, b);
}

// (L z)[r][c] with self value passed from register: only NEIGHBOR rows read from LDS.
__device__ __forceinline__ float lmix_n(const float* zbp, int S, int r, int c, float zself) {
  int e = r / 21;
  int n = r - e * 21;
  const float* rowb = zbp + e * 21 * S + c;
  float s = zself;
  float invd;
  if (n == 0) {
    s += rowb[1 * S] + rowb[5 * S] + rowb[9 * S] + rowb[13 * S] + rowb[17 * S];
    invd = 1.f / 6.f;
  } else {
    int p = (n - 1) & 3;
    if (p == 3) { s += rowb[(n - 1) * S]; invd = 0.5f; }
    else {
      int left = (p == 0) ? 0 : (n - 1);
      s += rowb[left * S] + rowb[(n + 1) * S];
      invd = 1.f / 3.f;
    }
  }
  return zself - invd * s;
}
// full version (self read from LDS) — used only in the tiny out phase
__device__ __forceinline__ float lmix(const float* zbp, int S, int r, int c) {
  int e = r / 21;
  int n = r - e * 21;
  const float* rowb = zbp + e * 21 * S + c;
  return lmix_n(zbp, S, r, c, rowb[n * S]);
}

__device__ __forceinline__ void mixone(char* sHc, const float* zbp, int r, int cu,
                                       float u, float zself, float bias) {
  float h = u + lmix_n(zbp, ZSTRIDE, r, cu, zself) + bias;
  h = (h > 0.f) ? h : 0.01f * h;
  *(uint16_t*)(sHc + swz(r * 256 + cu * 2, r)) = f2b(h);
}

// ---------------- prep: fp32 weights -> bf16 frag-layout in ws ----------------
__global__ void prep_weights(const float* __restrict__ W1, const float* __restrict__ W2,
                             const float* __restrict__ W3, uint16_t* __restrict__ ws) {
  uint16_t* wf1 = ws;
  uint16_t* wf2 = ws + 65536;
  uint16_t* wf3 = ws + 65536 + 32768;
  for (int i = blockIdx.x * blockDim.x + threadIdx.x; i < 100352;
       i += gridDim.x * blockDim.x) {
    if (i < 65536) {
      int n = i >> 8, k = i & 255;
      float v = (n < 128) ? W1[k * 128 + n] : W1[32768 + k * 128 + (n - 128)];
      wf1[i] = f2b(v);
    } else if (i < 98304) {
      int j = i - 65536; int n = j >> 7, k = j & 127;
      float v = (n < 128) ? W2[k * 128 + n] : W2[16384 + k * 128 + (n - 128)];
      wf2[j] = f2b(v);
    } else {
      int j = i - 98304; int n = j >> 7, k = j & 127;
      float v = 0.f;
      if (n < 3)      v = W3[k * 3 + n];
      else if (n < 6) v = W3[384 + k * 3 + (n - 3)];
      wf3[j] = f2b(v);
    }
  }
}

#define MFMA(d, va, vb) d = __builtin_amdgcn_mfma_f32_16x16x32_bf16(va, vb, d, 0, 0, 0)

#define ZST4(mt, v) { \
  const int rb_ = mt * 16 + lk * 4; \
  zb[(rb_ + 0) * ZSTRIDE + cu] = v[0]; \
  zb[(rb_ + 1) * ZSTRIDE + cu] = v[1]; \
  zb[(rb_ + 2) * ZSTRIDE + cu] = v[2]; \
  zb[(rb_ + 3) * ZSTRIDE + cu] = v[3]; \
}
#define ZST4G(mt, v) { \
  const int rb_ = mt * 16 + lk * 4; \
  if (rb_ + 0 < REAL_ROWS) zb[(rb_ + 0) * ZSTRIDE + cu] = v[0]; \
  if (rb_ + 1 < REAL_ROWS) zb[(rb_ + 1) * ZSTRIDE + cu] = v[1]; \
  if (rb_ + 2 < REAL_ROWS) zb[(rb_ + 2) * ZSTRIDE + cu] = v[2]; \
  if (rb_ + 3 < REAL_ROWS) zb[(rb_ + 3) * ZSTRIDE + cu] = v[3]; \
}
#define MIX4(mt, uv, zv, bias) { \
  const int rb_ = mt * 16 + lk * 4; \
  mixone(sHc, zb, rb_ + 0, cu, uv[0], zv[0], bias); \
  mixone(sHc, zb, rb_ + 1, cu, uv[1], zv[1], bias); \
  mixone(sHc, zb, rb_ + 2, cu, uv[2], zv[2], bias); \
  mixone(sHc, zb, rb_ + 3, cu, uv[3], zv[3], bias); \
}
#define MIX4G(mt, uv, zv, bias) { \
  const int rb_ = mt * 16 + lk * 4; \
  if (rb_ + 0 < REAL_ROWS) mixone(sHc, zb, rb_ + 0, cu, uv[0], zv[0], bias); \
  if (rb_ + 1 < REAL_ROWS) mixone(sHc, zb, rb_ + 1, cu, uv[1], zv[1], bias); \
  if (rb_ + 2 < REAL_ROWS) mixone(sHc, zb, rb_ + 2, cu, uv[2], zv[2], bias); \
  if (rb_ + 3 < REAL_ROWS) mixone(sHc, zb, rb_ + 3, cu, uv[3], zv[3], bias); \
}

// x tile: 42 rows x 32 octs = 1344 oct-items; groups j=0,1 full, j=2 partial
#define PF_ISSUE(p0, p1, j, src) { \
  const int i_ = tid + j * 512; \
  const int r_ = i_ >> 5, c8_ = (i_ & 31) * 8; \
  p0 = *(const float4*)(src + r_ * 256 + c8_); \
  p1 = *(const float4*)(src + r_ * 256 + c8_ + 4); \
}
#define PF_ISSUE_G(p0, p1, j, src) { \
  const int i_ = tid + j * 512; \
  if (i_ < 1344) { \
    const int r_ = i_ >> 5, c8_ = (i_ & 31) * 8; \
    p0 = *(const float4*)(src + r_ * 256 + c8_); \
    p1 = *(const float4*)(src + r_ * 256 + c8_ + 4); \
  } \
}
#define PF_WRITE(p0, p1, j) { \
  const int i_ = tid + j * 512; \
  const int r_ = i_ >> 5, c8_ = (i_ & 31) * 8; \
  bf16x8 o_; \
  o_[0] = (__bf16)p0.x; o_[1] = (__bf16)p0.y; o_[2] = (__bf16)p0.z; o_[3] = (__bf16)p0.w; \
  o_[4] = (__bf16)p1.x; o_[5] = (__bf16)p1.y; o_[6] = (__bf16)p1.z; o_[7] = (__bf16)p1.w; \
  *(bf16x8*)(sAc + swz(r_ * 512 + c8_ * 2, r_)) = o_; \
}
#define PF_WRITE_G(p0, p1, j) { \
  const int i_ = tid + j * 512; \
  if (i_ < 1344) { \
    const int r_ = i_ >> 5, c8_ = (i_ & 31) * 8; \
    bf16x8 o_; \
    o_[0] = (__bf16)p0.x; o_[1] = (__bf16)p0.y; o_[2] = (__bf16)p0.z; o_[3] = (__bf16)p0.w; \
    o_[4] = (__bf16)p1.x; o_[5] = (__bf16)p1.y; o_[6] = (__bf16)p1.z; o_[7] = (__bf16)p1.w; \
    *(bf16x8*)(sAc + swz(r_ * 512 + c8_ * 2, r_)) = o_; \
  } \
}

// ---------------- fused main ----------------
// R5 -> R6: TB 4->2 cuts LDS 117->59 KB => 2 independent blocks/CU (16 waves),
// prefetch issued BEFORE the L1 GEMM (HBM latency hidden under compute, not
// drained at a barrier), neighbor-only mix reads, 5 barriers/tile, zero spill.
__global__ __launch_bounds__(512)
void cheb3_main(const float* __restrict__ xp,
                const uint16_t* __restrict__ wf1, const uint16_t* __restrict__ wf2,
                const uint16_t* __restrict__ wf3,
                const float* __restrict__ b1p, const float* __restrict__ b2p,
                const float* __restrict__ b3p, float* __restrict__ outp)
{
  __shared__ __align__(16) uint16_t sA[RPAD * 256];     // x bf16, swizzled (24 KB)
  __shared__ __align__(16) uint16_t sH[RPAD * 128];     // h bf16, swizzled (12 KB)
  __shared__ float zb[REAL_ROWS * ZSTRIDE + 4 * REAL_ROWS];  // z fp32 + z3 region (22 KB)

  const int tid  = threadIdx.x;
  const int wid  = tid >> 6;
  const int lane = tid & 63;
  const int l15  = lane & 15;
  const int lk   = lane >> 4;
  char* sAc = (char*)sA;
  char* sHc = (char*)sH;

  const int nu = wid * 16 + l15;     // wave's u-column block
  const int cu = nu;
  const float bias1 = b1p[cu];
  const float bias2 = b2p[cu];
  const float bias3 = (l15 < 3) ? b3p[l15] : 0.f;

  // zero pad rows 42..47 (written once)
  {
    uint4 z16 = make_uint4(0, 0, 0, 0);
    for (int i = tid; i < (6 * 256) / 8; i += 512) {
      int f0 = i * 8, r = REAL_ROWS + (f0 >> 8), c = f0 & 255;
      *(uint4*)(sAc + swz(r * 512 + c * 2, r)) = z16;
    }
    for (int i = tid; i < (6 * 128) / 8; i += 512) {
      int f0 = i * 8, r = REAL_ROWS + (f0 >> 7), c = f0 & 127;
      *(uint4*)(sHc + swz(r * 256 + c * 2, r)) = z16;
    }
  }

  // stage tile 0 synchronously
  {
    const float* xg = xp + (size_t)(blockIdx.x * TILES) * (TB * N_JOINT * 256);
    #pragma unroll
    for (int j = 0; j < 3; ++j) {
      int i = tid + j * 512;
      if (i < 1344) {
        int r = i >> 5, c8 = (i & 31) * 8;
        float4 v0 = *(const float4*)(xg + r * 256 + c8);
        float4 v1 = *(const float4*)(xg + r * 256 + c8 + 4);
        bf16x8 o;
        o[0] = (__bf16)v0.x; o[1] = (__bf16)v0.y; o[2] = (__bf16)v0.z; o[3] = (__bf16)v0.w;
        o[4] = (__bf16)v1.x; o[5] = (__bf16)v1.y; o[6] = (__bf16)v1.z; o[7] = (__bf16)v1.w;
        *(bf16x8*)(sAc + swz(r * 512 + c8 * 2, r)) = o;
      }
    }
  }
  __syncthreads();

  const f32x4 zero4 = {0.f, 0.f, 0.f, 0.f};

  for (int t = 0; t < TILES; ++t) {
    const int gtile = blockIdx.x * TILES + t;
    const bool pf = (t + 1 < TILES);
    const float* xn = xp + (size_t)(gtile + 1) * (TB * N_JOINT * 256);

    // prefetch next x tile into regs FIRST: HBM latency hides under L1 GEMM
    float4 pA0, pA1, pA2, pA3, pA4, pA5;
    if (pf) { PF_ISSUE(pA0, pA1, 0, xn); PF_ISSUE(pA2, pA3, 1, xn); PF_ISSUE_G(pA4, pA5, 2, xn); }

    // ---------------- LAYER 1: sA[48][256] @ W1frag ----------------
    f32x4 u0 = zero4, u1 = zero4, u2 = zero4;
    f32x4 z0 = zero4, z1 = zero4, z2 = zero4;
    #pragma unroll 2
    for (int ch = 0; ch < 8; ++ch) {
      const bf16x8 wa_ = *(const bf16x8*)(wf1 + nu * 256 + ch * 32 + lk * 8);
      const bf16x8 wb_ = *(const bf16x8*)(wf1 + (nu + 128) * 256 + ch * 32 + lk * 8);
      const int kb_ = ch * 64 + lk * 16;
      bf16x8 a0_ = *(const bf16x8*)(sAc + swz((0*16 + l15) * 512 + kb_, 0*16 + l15));
      bf16x8 a1_ = *(const bf16x8*)(sAc + swz((1*16 + l15) * 512 + kb_, 1*16 + l15));
      bf16x8 a2_ = *(const bf16x8*)(sAc + swz((2*16 + l15) * 512 + kb_, 2*16 + l15));
      MFMA(u0, a0_, wa_); MFMA(u1, a1_, wa_); MFMA(u2, a2_, wa_);
      MFMA(z0, a0_, wb_); MFMA(z1, a1_, wb_); MFMA(z2, a2_, wb_);
    }

    ZST4(0, z0); ZST4(1, z1); ZST4G(2, z2);
    __syncthreads();                          // B1: z1 visible; L1 sA reads done

    if (pf) { PF_WRITE(pA0, pA1, 0); PF_WRITE(pA2, pA3, 1); PF_WRITE_G(pA4, pA5, 2); }
    MIX4(0, u0, z0, bias1); MIX4(1, u1, z1, bias1); MIX4G(2, u2, z2, bias1);
    __syncthreads();                          // B2: sH (h1) ready; sA staged

    // ---------------- LAYER 2: sH[48][128] @ W2frag ----------------
    u0 = zero4; u1 = zero4; u2 = zero4;
    z0 = zero4; z1 = zero4; z2 = zero4;
    #pragma unroll 2
    for (int ch = 0; ch < 4; ++ch) {
      const bf16x8 wa_ = *(const bf16x8*)(wf2 + nu * 128 + ch * 32 + lk * 8);
      const bf16x8 wb_ = *(const bf16x8*)(wf2 + (nu + 128) * 128 + ch * 32 + lk * 8);
      const int kb_ = ch * 64 + lk * 16;
      bf16x8 a0_ = *(const bf16x8*)(sHc + swz((0*16 + l15) * 256 + kb_, 0*16 + l15));
      bf16x8 a1_ = *(const bf16x8*)(sHc + swz((1*16 + l15) * 256 + kb_, 1*16 + l15));
      bf16x8 a2_ = *(const bf16x8*)(sHc + swz((2*16 + l15) * 256 + kb_, 2*16 + l15));
      MFMA(u0, a0_, wa_); MFMA(u1, a1_, wa_); MFMA(u2, a2_, wa_);
      MFMA(z0, a0_, wb_); MFMA(z1, a1_, wb_); MFMA(z2, a2_, wb_);
    }

    ZST4(0, z0); ZST4(1, z1); ZST4G(2, z2);
    __syncthreads();                          // B3: z2 visible; L2 sH reads done

    MIX4(0, u0, z0, bias2); MIX4(1, u1, z1, bias2); MIX4G(2, u2, z2, bias2);
    __syncthreads();                          // B4: sH (h2) ready; mix zb reads done

    // ---------------- LAYER 3: sH[48][128] @ W3frag (waves 0..2) ----------------
    f32x4 c3 = zero4;
    if (wid < 3) {
      #pragma unroll 1
      for (int ch = 0; ch < 4; ++ch) {
        const bf16x8 w3_ = *(const bf16x8*)(wf3 + l15 * 128 + ch * 32 + lk * 8);
        bf16x8 a3_ = *(const bf16x8*)(sHc + swz((wid * 16 + l15) * 256 + ch * 64 + lk * 16, wid * 16 + l15));
        MFMA(c3, a3_, w3_);
      }
    }
    if (wid < 3 && l15 >= 3 && l15 < 6) {     // z3 -> disjoint zb region
      const int rb_ = wid * 16 + lk * 4;
      if (rb_ + 0 < REAL_ROWS) zb[Z3OFF + (rb_ + 0) * 4 + (l15 - 3)] = c3[0];
      if (rb_ + 1 < REAL_ROWS) zb[Z3OFF + (rb_ + 1) * 4 + (l15 - 3)] = c3[1];
      if (rb_ + 2 < REAL_ROWS) zb[Z3OFF + (rb_ + 2) * 4 + (l15 - 3)] = c3[2];
      if (rb_ + 3 < REAL_ROWS) zb[Z3OFF + (rb_ + 3) * 4 + (l15 - 3)] = c3[3];
    }
    __syncthreads();                          // B5: z3 visible
    if (wid < 3 && l15 < 3) {
      const int rb_ = wid * 16 + lk * 4;
      #define OUT1(rg) { \
        int r = rb_ + rg; \
        if (r < REAL_ROWS) { \
          float v = c3[rg] + lmix(zb + Z3OFF, 4, r, l15) + bias3; \
          int e = r / 21, n = r - e * 21; \
          outp[((size_t)(gtile * TB + e) * N_JOINT + n) * 3 + l15] = v; \
        } \
      }
      OUT1(0); OUT1(1); OUT1(2); OUT1(3);
      #undef OUT1
    }
    // no barrier here: next tile's zb writes come after B1; z3 region is
    // disjoint and next written only after next tile's B4.
  }
}

extern "C" void kernel_launch(void* const* d_in, const int* in_sizes, int n_in,
                              void* d_out, int out_size, void* d_ws, size_t ws_size,
                              hipStream_t stream) {
  const float* xp  = (const float*)d_in[0];
  const float* W1p = (const float*)d_in[1];
  const float* b1p = (const float*)d_in[2];
  const float* W2p = (const float*)d_in[3];
  const float* b2p = (const float*)d_in[4];
  const float* W3p = (const float*)d_in[5];
  const float* b3p = (const float*)d_in[6];
  uint16_t* ws = (uint16_t*)d_ws;

  hipLaunchKernelGGL(prep_weights, dim3(196), dim3(512), 0, stream, W1p, W2p, W3p, ws);

  const uint16_t* wf1 = ws;
  const uint16_t* wf2 = ws + 65536;
  const uint16_t* wf3 = ws + 65536 + 32768;
  hipLaunchKernelGGL(cheb3_main, dim3(NBLK), dim3(512), 0, stream,
                     xp, wf1, wf2, wf3, b1p, b2p, b3p, (float*)d_out);
}

// Round 7
// 316.362 us; speedup vs baseline: 3.4230x; 1.0359x over previous
//
#include <hip/hip_runtime.h>
#include <stdint.h>

typedef __bf16 bf16x8 __attribute__((ext_vector_type(8)));
typedef float  f32x4  __attribute__((ext_vector_type(4)));

#define N_JOINT 21
#define TB 2
#define REAL_ROWS 42               // 21*2
#define RPAD 48                    // 3 MFMA M-tiles
#define BATCH 16384
#define TILES 16                   // tiles per block
#define NBLK (BATCH / (TB * TILES))   // 512 blocks
#define ZSTRIDE 129                // odd stride: bank = (r+c)%32

__device__ __forceinline__ uint32_t swz(uint32_t byteoff, uint32_t row) {
  return byteoff ^ ((row & 7u) << 4);
}
__device__ __forceinline__ uint16_t f2b(float v) {
  __bf16 b = (__bf16)v;
  return __builtin_bit_cast(uint16_t, b);
}

// (L z)[r][c] with self value in register: only NEIGHBOR rows read from LDS.
__device__ __forceinline__ float lmix_n(const float* zbp, int S, int r, int c, float zself) {
  int e = r / 21;
  int n = r - e * 21;
  const float* rowb = zbp + e * 21 * S + c;
  float s = zself;
  float invd;
  if (n == 0) {
    s += rowb[1 * S] + rowb[5 * S] + rowb[9 * S] + rowb[13 * S] + rowb[17 * S];
    invd = 1.f / 6.f;
  } else {
    int p = (n - 1) & 3;
    if (p == 3) { s += rowb[(n - 1) * S]; invd = 0.5f; }
    else {
      int left = (p == 0) ? 0 : (n - 1);
      s += rowb[left * S] + rowb[(n + 1) * S];
      invd = 1.f / 3.f;
    }
  }
  return zself - invd * s;
}

__device__ __forceinline__ void mixone(char* dst, const float* zbp, int r, int cu,
                                       float u, float zself, float bias) {
  float h = u + lmix_n(zbp, ZSTRIDE, r, cu, zself) + bias;
  h = (h > 0.f) ? h : 0.01f * h;
  *(uint16_t*)(dst + swz(r * 256 + cu * 2, r)) = f2b(h);
}

// ---------------- prep: fp32 weights -> bf16 frag-layout in ws ----------------
__global__ void prep_weights(const float* __restrict__ W1, const float* __restrict__ W2,
                             const float* __restrict__ W3, uint16_t* __restrict__ ws) {
  uint16_t* wf1 = ws;
  uint16_t* wf2 = ws + 65536;
  uint16_t* wf3 = ws + 65536 + 32768;
  for (int i = blockIdx.x * blockDim.x + threadIdx.x; i < 100352;
       i += gridDim.x * blockDim.x) {
    if (i < 65536) {
      int n = i >> 8, k = i & 255;
      float v = (n < 128) ? W1[k * 128 + n] : W1[32768 + k * 128 + (n - 128)];
      wf1[i] = f2b(v);
    } else if (i < 98304) {
      int j = i - 65536; int n = j >> 7, k = j & 127;
      float v = (n < 128) ? W2[k * 128 + n] : W2[16384 + k * 128 + (n - 128)];
      wf2[j] = f2b(v);
    } else {
      int j = i - 98304; int n = j >> 7, k = j & 127;
      float v = 0.f;
      if (n < 3)      v = W3[k * 3 + n];
      else if (n < 6) v = W3[384 + k * 3 + (n - 3)];
      wf3[j] = f2b(v);
    }
  }
}

#define MFMA(d, va, vb) d = __builtin_amdgcn_mfma_f32_16x16x32_bf16(va, vb, d, 0, 0, 0)

#define ZST4(mt, v) { \
  const int rb_ = mt * 16 + lk * 4; \
  zb[(rb_ + 0) * ZSTRIDE + cu] = v[0]; \
  zb[(rb_ + 1) * ZSTRIDE + cu] = v[1]; \
  zb[(rb_ + 2) * ZSTRIDE + cu] = v[2]; \
  zb[(rb_ + 3) * ZSTRIDE + cu] = v[3]; \
}
#define ZST4G(mt, v) { \
  const int rb_ = mt * 16 + lk * 4; \
  if (rb_ + 0 < REAL_ROWS) zb[(rb_ + 0) * ZSTRIDE + cu] = v[0]; \
  if (rb_ + 1 < REAL_ROWS) zb[(rb_ + 1) * ZSTRIDE + cu] = v[1]; \
  if (rb_ + 2 < REAL_ROWS) zb[(rb_ + 2) * ZSTRIDE + cu] = v[2]; \
  if (rb_ + 3 < REAL_ROWS) zb[(rb_ + 3) * ZSTRIDE + cu] = v[3]; \
}
#define MIX4(dst, mt, uv, zv, bias) { \
  const int rb_ = mt * 16 + lk * 4; \
  mixone(dst, zb, rb_ + 0, cu, uv[0], zv[0], bias); \
  mixone(dst, zb, rb_ + 1, cu, uv[1], zv[1], bias); \
  mixone(dst, zb, rb_ + 2, cu, uv[2], zv[2], bias); \
  mixone(dst, zb, rb_ + 3, cu, uv[3], zv[3], bias); \
}
#define MIX4G(dst, mt, uv, zv, bias) { \
  const int rb_ = mt * 16 + lk * 4; \
  if (rb_ + 0 < REAL_ROWS) mixone(dst, zb, rb_ + 0, cu, uv[0], zv[0], bias); \
  if (rb_ + 1 < REAL_ROWS) mixone(dst, zb, rb_ + 1, cu, uv[1], zv[1], bias); \
  if (rb_ + 2 < REAL_ROWS) mixone(dst, zb, rb_ + 2, cu, uv[2], zv[2], bias); \
  if (rb_ + 3 < REAL_ROWS) mixone(dst, zb, rb_ + 3, cu, uv[3], zv[3], bias); \
}

// x tile: 42 rows x 32 octs = 1344 oct-items
#define PF_ISSUE(p0, p1, j, src) { \
  const int i_ = tid + j * 512; \
  const int r_ = i_ >> 5, c8_ = (i_ & 31) * 8; \
  p0 = *(const float4*)(src + r_ * 256 + c8_); \
  p1 = *(const float4*)(src + r_ * 256 + c8_ + 4); \
}
#define PF_ISSUE_G(p0, p1, j, src) { \
  const int i_ = tid + j * 512; \
  if (i_ < 1344) { \
    const int r_ = i_ >> 5, c8_ = (i_ & 31) * 8; \
    p0 = *(const float4*)(src + r_ * 256 + c8_); \
    p1 = *(const float4*)(src + r_ * 256 + c8_ + 4); \
  } \
}
#define PF_WRITE(p0, p1, j) { \
  const int i_ = tid + j * 512; \
  const int r_ = i_ >> 5, c8_ = (i_ & 31) * 8; \
  bf16x8 o_; \
  o_[0] = (__bf16)p0.x; o_[1] = (__bf16)p0.y; o_[2] = (__bf16)p0.z; o_[3] = (__bf16)p0.w; \
  o_[4] = (__bf16)p1.x; o_[5] = (__bf16)p1.y; o_[6] = (__bf16)p1.z; o_[7] = (__bf16)p1.w; \
  *(bf16x8*)(sAc + swz(r_ * 512 + c8_ * 2, r_)) = o_; \
}
#define PF_WRITE_G(p0, p1, j) { \
  const int i_ = tid + j * 512; \
  if (i_ < 1344) { \
    const int r_ = i_ >> 5, c8_ = (i_ & 31) * 8; \
    bf16x8 o_; \
    o_[0] = (__bf16)p0.x; o_[1] = (__bf16)p0.y; o_[2] = (__bf16)p0.z; o_[3] = (__bf16)p0.w; \
    o_[4] = (__bf16)p1.x; o_[5] = (__bf16)p1.y; o_[6] = (__bf16)p1.z; o_[7] = (__bf16)p1.w; \
    *(bf16x8*)(sAc + swz(r_ * 512 + c8_ * 2, r_)) = o_; \
  } \
}

// ---------------- fused main ----------------
// R6 -> R7: z-exchange is WAVE-LOCAL (each wave computes all 48 rows of its own
// 16 columns; the graph mix reads only same-column neighbor rows -> its own zb
// writes, ordered by lgkmcnt). Barriers per tile: 5 -> 2. Layer 3 runs on wave 0
// alone after the 2nd barrier (z3 exchange also wave-local); waves 1-7 run
// ahead into the next tile. mix2 -> separate sH2 buffer (no WAR with L2 reads).
__global__ __launch_bounds__(512)
void cheb3_main(const float* __restrict__ xp,
                const uint16_t* __restrict__ wf1, const uint16_t* __restrict__ wf2,
                const uint16_t* __restrict__ wf3,
                const float* __restrict__ b1p, const float* __restrict__ b2p,
                const float* __restrict__ b3p, float* __restrict__ outp)
{
  __shared__ __align__(16) uint16_t sA[RPAD * 256];    // x bf16, swizzled (24 KB)
  __shared__ __align__(16) uint16_t sH[RPAD * 128];    // h1 bf16 (12 KB)
  __shared__ __align__(16) uint16_t sH2[RPAD * 128];   // h2 bf16 (12 KB)
  __shared__ float zb[REAL_ROWS * ZSTRIDE];            // z fp32, wave-local exchange (21.7 KB)
  __shared__ float zb2[REAL_ROWS * 4];                 // z3, wave0-local (0.7 KB)

  const int tid  = threadIdx.x;
  const int wid  = tid >> 6;
  const int lane = tid & 63;
  const int l15  = lane & 15;
  const int lk   = lane >> 4;
  char* sAc  = (char*)sA;
  char* sHc  = (char*)sH;
  char* sH2c = (char*)sH2;

  const int nu = wid * 16 + l15;     // wave's u-column block
  const int cu = nu;
  const float bias1 = b1p[cu];
  const float bias2 = b2p[cu];
  const float bias3 = (l15 < 3) ? b3p[l15] : 0.f;

  // zero pad rows 42..47 (written once)
  {
    uint4 z16 = make_uint4(0, 0, 0, 0);
    for (int i = tid; i < (6 * 256) / 8; i += 512) {
      int f0 = i * 8, r = REAL_ROWS + (f0 >> 8), c = f0 & 255;
      *(uint4*)(sAc + swz(r * 512 + c * 2, r)) = z16;
    }
    for (int i = tid; i < (6 * 128) / 8; i += 512) {
      int f0 = i * 8, r = REAL_ROWS + (f0 >> 7), c = f0 & 127;
      *(uint4*)(sHc + swz(r * 256 + c * 2, r)) = z16;
      *(uint4*)(sH2c + swz(r * 256 + c * 2, r)) = z16;
    }
  }

  // stage tile 0 synchronously
  {
    const float* xg = xp + (size_t)(blockIdx.x * TILES) * (TB * N_JOINT * 256);
    #pragma unroll
    for (int j = 0; j < 3; ++j) {
      int i = tid + j * 512;
      if (i < 1344) {
        int r = i >> 5, c8 = (i & 31) * 8;
        float4 v0 = *(const float4*)(xg + r * 256 + c8);
        float4 v1 = *(const float4*)(xg + r * 256 + c8 + 4);
        bf16x8 o;
        o[0] = (__bf16)v0.x; o[1] = (__bf16)v0.y; o[2] = (__bf16)v0.z; o[3] = (__bf16)v0.w;
        o[4] = (__bf16)v1.x; o[5] = (__bf16)v1.y; o[6] = (__bf16)v1.z; o[7] = (__bf16)v1.w;
        *(bf16x8*)(sAc + swz(r * 512 + c8 * 2, r)) = o;
      }
    }
  }
  __syncthreads();

  const f32x4 zero4 = {0.f, 0.f, 0.f, 0.f};

  for (int t = 0; t < TILES; ++t) {
    const int gtile = blockIdx.x * TILES + t;
    const bool pf = (t + 1 < TILES);
    const float* xn = xp + (size_t)(gtile + 1) * (TB * N_JOINT * 256);

    // prefetch next x tile into regs: HBM latency hides under L1 GEMM
    float4 pA0, pA1, pA2, pA3, pA4, pA5;
    if (pf) { PF_ISSUE(pA0, pA1, 0, xn); PF_ISSUE(pA2, pA3, 1, xn); PF_ISSUE_G(pA4, pA5, 2, xn); }

    // ---------------- LAYER 1: sA[48][256] @ W1frag ----------------
    f32x4 u0 = zero4, u1 = zero4, u2 = zero4;
    f32x4 z0 = zero4, z1 = zero4, z2 = zero4;
    #pragma unroll 2
    for (int ch = 0; ch < 8; ++ch) {
      const bf16x8 wa_ = *(const bf16x8*)(wf1 + nu * 256 + ch * 32 + lk * 8);
      const bf16x8 wb_ = *(const bf16x8*)(wf1 + (nu + 128) * 256 + ch * 32 + lk * 8);
      const int kb_ = ch * 64 + lk * 16;
      bf16x8 a0_ = *(const bf16x8*)(sAc + swz((0*16 + l15) * 512 + kb_, 0*16 + l15));
      bf16x8 a1_ = *(const bf16x8*)(sAc + swz((1*16 + l15) * 512 + kb_, 1*16 + l15));
      bf16x8 a2_ = *(const bf16x8*)(sAc + swz((2*16 + l15) * 512 + kb_, 2*16 + l15));
      MFMA(u0, a0_, wa_); MFMA(u1, a1_, wa_); MFMA(u2, a2_, wa_);
      MFMA(z0, a0_, wb_); MFMA(z1, a1_, wb_); MFMA(z2, a2_, wb_);
    }

    // mix1: entirely wave-local (own columns, lgkmcnt-ordered)
    ZST4(0, z0); ZST4(1, z1); ZST4G(2, z2);
    MIX4(sHc, 0, u0, z0, bias1); MIX4(sHc, 1, u1, z1, bias1); MIX4G(sHc, 2, u2, z2, bias1);
    __syncthreads();                          // B1: h1 visible; all L1 sA reads done

    // restage sA for next tile (sA free), overlapping L2 GEMM below
    if (pf) { PF_WRITE(pA0, pA1, 0); PF_WRITE(pA2, pA3, 1); PF_WRITE_G(pA4, pA5, 2); }

    // ---------------- LAYER 2: sH[48][128] @ W2frag ----------------
    u0 = zero4; u1 = zero4; u2 = zero4;
    z0 = zero4; z1 = zero4; z2 = zero4;
    #pragma unroll 2
    for (int ch = 0; ch < 4; ++ch) {
      const bf16x8 wa_ = *(const bf16x8*)(wf2 + nu * 128 + ch * 32 + lk * 8);
      const bf16x8 wb_ = *(const bf16x8*)(wf2 + (nu + 128) * 128 + ch * 32 + lk * 8);
      const int kb_ = ch * 64 + lk * 16;
      bf16x8 a0_ = *(const bf16x8*)(sHc + swz((0*16 + l15) * 256 + kb_, 0*16 + l15));
      bf16x8 a1_ = *(const bf16x8*)(sHc + swz((1*16 + l15) * 256 + kb_, 1*16 + l15));
      bf16x8 a2_ = *(const bf16x8*)(sHc + swz((2*16 + l15) * 256 + kb_, 2*16 + l15));
      MFMA(u0, a0_, wa_); MFMA(u1, a1_, wa_); MFMA(u2, a2_, wa_);
      MFMA(z0, a0_, wb_); MFMA(z1, a1_, wb_); MFMA(z2, a2_, wb_);
    }

    // mix2: wave-local, writes h2 into sH2 (no WAR with L2's sH reads)
    ZST4(0, z0); ZST4(1, z1); ZST4G(2, z2);
    MIX4(sH2c, 0, u0, z0, bias2); MIX4(sH2c, 1, u1, z1, bias2); MIX4G(sH2c, 2, u2, z2, bias2);
    __syncthreads();                          // B2: h2 visible; L2 sH reads + sA writes done

    // ---------------- LAYER 3: wave 0 only; waves 1-7 run ahead ----------------
    if (wid == 0) {
      f32x4 c30 = zero4, c31 = zero4, c32 = zero4;
      #pragma unroll 1
      for (int ch = 0; ch < 4; ++ch) {
        const bf16x8 w3_ = *(const bf16x8*)(wf3 + l15 * 128 + ch * 32 + lk * 8);
        bf16x8 a0_ = *(const bf16x8*)(sH2c + swz((0*16 + l15) * 256 + ch * 64 + lk * 16, 0*16 + l15));
        bf16x8 a1_ = *(const bf16x8*)(sH2c + swz((1*16 + l15) * 256 + ch * 64 + lk * 16, 1*16 + l15));
        bf16x8 a2_ = *(const bf16x8*)(sH2c + swz((2*16 + l15) * 256 + ch * 64 + lk * 16, 2*16 + l15));
        MFMA(c30, a0_, w3_); MFMA(c31, a1_, w3_); MFMA(c32, a2_, w3_);
      }
      if (l15 >= 3 && l15 < 6) {              // z3 -> zb2 (wave0-local)
        #define Z3ST(mt, v) { \
          const int rb_ = mt * 16 + lk * 4; \
          if (rb_ + 0 < REAL_ROWS) zb2[(rb_ + 0) * 4 + (l15 - 3)] = v[0]; \
          if (rb_ + 1 < REAL_ROWS) zb2[(rb_ + 1) * 4 + (l15 - 3)] = v[1]; \
          if (rb_ + 2 < REAL_ROWS) zb2[(rb_ + 2) * 4 + (l15 - 3)] = v[2]; \
          if (rb_ + 3 < REAL_ROWS) zb2[(rb_ + 3) * 4 + (l15 - 3)] = v[3]; \
        }
        Z3ST(0, c30); Z3ST(1, c31); Z3ST(2, c32);
        #undef Z3ST
      }
      if (l15 < 3) {
        #define OUT3(mt, v) { \
          const int rb_ = mt * 16 + lk * 4; \
          _Pragma("unroll") \
          for (int rg = 0; rg < 4; ++rg) { \
            int r = rb_ + rg; \
            if (r < REAL_ROWS) { \
              int e = r / 21, n = r - e * 21; \
              float zs = zb2[r * 4 + l15]; \
              float vv = v[rg] + lmix_n(zb2, 4, r, l15, zs) + bias3; \
              outp[((size_t)(gtile * TB + e) * N_JOINT + n) * 3 + l15] = vv; \
            } \
          } \
        }
        OUT3(0, c30); OUT3(1, c31); OUT3(2, c32);
        #undef OUT3
      }
    }
    // no further barrier: next tile's sH writes happen after next B1-equivalent
    // ordering (mix1 writes sH which L2(t) readers finished before B2; wave0's
    // sH2 reads finish before it joins the next B1).
  }
}

extern "C" void kernel_launch(void* const* d_in, const int* in_sizes, int n_in,
                              void* d_out, int out_size, void* d_ws, size_t ws_size,
                              hipStream_t stream) {
  const float* xp  = (const float*)d_in[0];
  const float* W1p = (const float*)d_in[1];
  const float* b1p = (const float*)d_in[2];
  const float* W2p = (const float*)d_in[3];
  const float* b2p = (const float*)d_in[4];
  const float* W3p = (const float*)d_in[5];
  const float* b3p = (const float*)d_in[6];
  uint16_t* ws = (uint16_t*)d_ws;

  hipLaunchKernelGGL(prep_weights, dim3(196), dim3(512), 0, stream, W1p, W2p, W3p, ws);

  const uint16_t* wf1 = ws;
  const uint16_t* wf2 = ws + 65536;
  const uint16_t* wf3 = ws + 65536 + 32768;
  hipLaunchKernelGGL(cheb3_main, dim3(NBLK), dim3(512), 0, stream,
                     xp, wf1, wf2, wf3, b1p, b2p, b3p, (float*)d_out);
}